// Round 2
// baseline (486.975 us; speedup 1.0000x reference)
//
#include <hip/hip_runtime.h>
#include <stdint.h>

typedef __bf16 bf8 __attribute__((ext_vector_type(8)));
typedef float f4 __attribute__((ext_vector_type(4)));
typedef unsigned short us4 __attribute__((ext_vector_type(4)));
typedef unsigned short us8 __attribute__((ext_vector_type(8)));
typedef float fl4 __attribute__((ext_vector_type(4)));

#define NB 4096      // batch
#define NS 10        // context tokens
#define NE 512       // embed
#define NH 2048      // hidden
#define BS 40960     // NB*NS

__device__ __forceinline__ unsigned short f2bf(float f) {
    uint32_t u = __builtin_bit_cast(uint32_t, f);
    u += 0x7FFFu + ((u >> 16) & 1u);
    return (unsigned short)(u >> 16);
}
__device__ __forceinline__ __bf16 bfb(unsigned short u) { return __builtin_bit_cast(__bf16, u); }

__device__ __forceinline__ void gl_lds16(const void* g, void* l) {
    __builtin_amdgcn_global_load_lds((const __attribute__((address_space(1))) uint32_t*)g,
                                     (__attribute__((address_space(3))) uint32_t*)l, 16, 0, 0);
}

// ---------------- prep: gather emb rows + cast weights, all -> bf16 ----------------
// vec4 ranges: Xt 524288 | Xc 5242880 | Wq/Wk/Wv 262144 each  => 6,553,600 total
__global__ __launch_bounds__(256) void prep_kernel(
    const int* __restrict__ t, const int* __restrict__ c, const float* __restrict__ emb,
    const float* __restrict__ Wq, const float* __restrict__ Wk, const float* __restrict__ Wv,
    unsigned short* __restrict__ Xt, unsigned short* __restrict__ Xc,
    unsigned short* __restrict__ wQ, unsigned short* __restrict__ wK, unsigned short* __restrict__ wV)
{
    int v = blockIdx.x * 256 + threadIdx.x;
    const float* src;
    unsigned short* dst;
    if (v < 524288) {
        int e4 = v << 2; int row = e4 >> 9;
        src = emb + (size_t)t[row] * NE + (e4 & 511);
        dst = Xt + e4;
    } else if (v < 5767168) {
        int vv = v - 524288; int e4 = vv << 2; int row = e4 >> 9;
        src = emb + (size_t)c[row] * NE + (e4 & 511);
        dst = Xc + e4;
    } else {
        int vv = v - 5767168; int which = vv >> 18; int e4 = (vv & 262143) << 2;
        src = (which == 0 ? Wq : (which == 1 ? Wk : Wv)) + e4;
        dst = (which == 0 ? wQ : (which == 1 ? wK : wV)) + e4;
    }
    fl4 f = *(const fl4*)src;
    us4 o;
    o[0] = f2bf(f[0]); o[1] = f2bf(f[1]); o[2] = f2bf(f[2]); o[3] = f2bf(f[3]);
    *(us4*)dst = o;
}

// ---------------- GEMM: Y[m,n] = sum_k A[m,k]*W[n,k] + bias[n] ----------------
// 128x128 tile, BK=64, 256 thr (4 waves, 2x2 of 64x64), K=512 (8 steps).
// Segments by blockIdx: [0,512) Xt*Wq->Q bf16 | [512,1024) Xt*Wv->TV f32 (d_out)
//                       [1024,6144) Xc*Wk->K bf16 | [6144,11264) Xc*Wv->V bf16
__global__ __launch_bounds__(256, 2) void gemm_all(
    const unsigned short* __restrict__ Xt, const unsigned short* __restrict__ Xc,
    const unsigned short* __restrict__ wQ, const unsigned short* __restrict__ wK,
    const unsigned short* __restrict__ wV,
    const float* __restrict__ bq, const float* __restrict__ bk, const float* __restrict__ bv,
    unsigned short* __restrict__ Qb, unsigned short* __restrict__ Kb, unsigned short* __restrict__ Vb,
    float* __restrict__ TV)
{
    int id = blockIdx.x;
    const unsigned short* A; const unsigned short* W; const float* bias;
    unsigned short* outb = nullptr; float* outf = nullptr;
    int tile;
    if (id < 512)       { A = Xt; W = wQ; bias = bq; outb = Qb; tile = id; }
    else if (id < 1024) { A = Xt; W = wV; bias = bv; outf = TV; tile = id - 512; }
    else if (id < 6144) { A = Xc; W = wK; bias = bk; outb = Kb; tile = id - 1024; }
    else                { A = Xc; W = wV; bias = bv; outb = Vb; tile = id - 6144; }
    int mt = tile >> 4, nt = tile & 15;
    int m0 = mt * 128, n0 = nt * 128;

    __shared__ unsigned short Asm[128 * 64];
    __shared__ unsigned short Bsm[128 * 64];

    int tid = threadIdx.x;
    int lane = tid & 63, wid = tid >> 6;
    int hi = lane >> 4, lo = lane & 15;
    int wm = (wid >> 1) * 64, wn = (wid & 1) * 64;

    f4 acc[4][4] = {};

    for (int ks = 0; ks < 8; ++ks) {
        int k0 = ks * 64;
        // stage A and B tiles: 128 rows x 64 bf16 each; chunk = 16B (8 elems)
        for (int i = 0; i < 4; ++i) {
            int ci = (i << 8) + tid;            // 0..1023
            int row = ci >> 3, ch = ci & 7;
            const unsigned short* ga = A + (size_t)(m0 + row) * NE + k0 + ch * 8;
            gl_lds16(ga, Asm + ((i << 8) + (tid & ~63)) * 8);
        }
        for (int i = 0; i < 4; ++i) {
            int ci = (i << 8) + tid;
            int row = ci >> 3, ch = ci & 7;
            const unsigned short* gb = W + (size_t)(n0 + row) * NE + k0 + ch * 8;
            gl_lds16(gb, Bsm + ((i << 8) + (tid & ~63)) * 8);
        }
        __syncthreads();
        for (int kk = 0; kk < 2; ++kk) {
            bf8 a[4], b[4];
            for (int mi = 0; mi < 4; ++mi)
                a[mi] = *(const bf8*)&Asm[(wm + mi * 16 + lo) * 64 + kk * 32 + hi * 8];
            for (int ni = 0; ni < 4; ++ni)
                b[ni] = *(const bf8*)&Bsm[(wn + ni * 16 + lo) * 64 + kk * 32 + hi * 8];
            for (int mi = 0; mi < 4; ++mi)
                for (int ni = 0; ni < 4; ++ni)
                    acc[mi][ni] = __builtin_amdgcn_mfma_f32_16x16x32_bf16(a[mi], b[ni], acc[mi][ni], 0, 0, 0);
        }
        __syncthreads();
    }

    // epilogue: D row = hi*4+r (m), col = lo (n)  [m89-verified C/D layout]
    for (int mi = 0; mi < 4; ++mi)
        for (int ni = 0; ni < 4; ++ni) {
            int n = n0 + wn + ni * 16 + lo;
            float bb = bias[n];
            for (int r = 0; r < 4; ++r) {
                int m = m0 + wm + mi * 16 + hi * 4 + r;
                float vv = acc[mi][ni][r] + bb;
                if (outb) outb[(size_t)m * NH + n] = f2bf(vv);
                else      outf[(size_t)m * NH + n] = vv;
            }
        }
}

// ---------------- attention: 1 wave per b ----------------
// scores S^T[q][p] = sum_d K[q,d]*Q[p,d] via mfma(A=K, B=Q): D row=q=hi*4+r, col=p=lo.
// softmax over q = per-lane over r + shfl_xor(16,32). W stays lane-local:
// PV A-operand slot j (j<4) holds w[q=4*hi+j], slots 4..7 zero; B-operand slot j
// reads V[q=4*hi+j][d'] from LDS subtiles. Contraction pairs slots, so any true
// k-wiring gives sum_q w[q]*V[q][d'].
__global__ __launch_bounds__(256, 2) void attn_kernel(
    const unsigned short* __restrict__ Qb, const unsigned short* __restrict__ Kb,
    const unsigned short* __restrict__ Vb, float* __restrict__ CV)
{
    __shared__ unsigned short Vl[4][2048];   // per-wave: 8 subtiles [16 q][16 d']
    int tid = threadIdx.x, lane = tid & 63, wid = tid >> 6;
    int hi = lane >> 4, lo = lane & 15;
    int b = blockIdx.x * 4 + wid;

    const unsigned short* qrow = Qb + (size_t)b * NH;
    bf8 qf[4];
    for (int kk = 0; kk < 4; ++kk)
        qf[kk] = *(const bf8*)&qrow[lo * 128 + kk * 32 + hi * 8];

    f4 acc[8] = {};
    const float sc = 0.08838834764831845f;   // 1/sqrt(128)

    for (int s = 0; s < NS; ++s) {
        const unsigned short* vrow = Vb + ((size_t)b * NS + s) * NH;
        const unsigned short* krow = Kb + ((size_t)b * NS + s) * NH;

        // stage V row (16 q x 128 d bf16) into subtiles [t][q][16]
        for (int it = 0; it < 4; ++it) {
            int cc = lane + 64 * it;                 // 0..255 chunks of 8 elems
            int q_ = cc >> 4, rem = cc & 15, tt = rem >> 1, e = rem & 1;
            us8 d = *(const us8*)&vrow[cc * 8];
            *(us8*)&Vl[wid][tt * 256 + q_ * 16 + e * 8] = d;
        }

        // scores
        f4 st = {};
        for (int kk = 0; kk < 4; ++kk) {
            bf8 kf = *(const bf8*)&krow[lo * 128 + kk * 32 + hi * 8];
            st = __builtin_amdgcn_mfma_f32_16x16x32_bf16(kf, qf[kk], st, 0, 0, 0);
        }
        float e0 = st[0] * sc, e1 = st[1] * sc, e2 = st[2] * sc, e3 = st[3] * sc;
        float mx = fmaxf(fmaxf(e0, e1), fmaxf(e2, e3));
        mx = fmaxf(mx, __shfl_xor(mx, 16));
        mx = fmaxf(mx, __shfl_xor(mx, 32));
        float w0 = __expf(e0 - mx), w1 = __expf(e1 - mx), w2 = __expf(e2 - mx), w3 = __expf(e3 - mx);
        float sm = w0 + w1 + w2 + w3;
        sm += __shfl_xor(sm, 16);
        sm += __shfl_xor(sm, 32);
        float inv = 1.0f / sm;

        bf8 ap;
        ap[0] = (__bf16)(w0 * inv); ap[1] = (__bf16)(w1 * inv);
        ap[2] = (__bf16)(w2 * inv); ap[3] = (__bf16)(w3 * inv);
        ap[4] = (__bf16)0.0f; ap[5] = (__bf16)0.0f; ap[6] = (__bf16)0.0f; ap[7] = (__bf16)0.0f;

        // PV over 8 d-tiles
        for (int tt = 0; tt < 8; ++tt) {
            const unsigned short* base = &Vl[wid][tt * 256 + hi * 64 + lo];
            bf8 bv_;
            bv_[0] = bfb(base[0]);  bv_[1] = bfb(base[16]);
            bv_[2] = bfb(base[32]); bv_[3] = bfb(base[48]);
            bv_[4] = (__bf16)0.0f; bv_[5] = (__bf16)0.0f; bv_[6] = (__bf16)0.0f; bv_[7] = (__bf16)0.0f;
            acc[tt] = __builtin_amdgcn_mfma_f32_16x16x32_bf16(ap, bv_, acc[tt], 0, 0, 0);
        }
    }

    float* out = CV + (size_t)b * NH;
    for (int tt = 0; tt < 8; ++tt)
        for (int r = 0; r < 4; ++r)
            out[(hi * 4 + r) * 128 + tt * 16 + lo] = acc[tt][r];
}

// ---------------- launch ----------------
extern "C" void kernel_launch(void* const* d_in, const int* in_sizes, int n_in,
                              void* d_out, int out_size, void* d_ws, size_t ws_size,
                              hipStream_t stream) {
    const int*   t   = (const int*)d_in[0];
    const int*   c   = (const int*)d_in[1];
    const float* emb = (const float*)d_in[2];
    const float* Wq  = (const float*)d_in[3];
    const float* bq  = (const float*)d_in[4];
    const float* Wk  = (const float*)d_in[5];
    const float* bk  = (const float*)d_in[6];
    const float* Wv  = (const float*)d_in[7];
    const float* bv  = (const float*)d_in[8];
    float* out = (float*)d_out;

    char* ws = (char*)d_ws;
    unsigned short* Xt = (unsigned short*)(ws);                 //  4,194,304 B
    unsigned short* Xc = (unsigned short*)(ws + 4194304);       // 41,943,040 B
    unsigned short* wQ = (unsigned short*)(ws + 46137344);      //  2,097,152 B
    unsigned short* wK = (unsigned short*)(ws + 48234496);      //  2,097,152 B
    unsigned short* wV = (unsigned short*)(ws + 50331648);      //  2,097,152 B
    unsigned short* Qb = (unsigned short*)(ws + 52428800);      // 16,777,216 B
    unsigned short* Kb = (unsigned short*)(ws + 69206016);      // 167,772,160 B
    unsigned short* Vb = (unsigned short*)(ws + 236978176);     // 167,772,160 B -> end 404,750,336

    prep_kernel<<<25600, 256, 0, stream>>>(t, c, emb, Wq, Wk, Wv, Xt, Xc, wQ, wK, wV);
    gemm_all<<<11264, 256, 0, stream>>>(Xt, Xc, wQ, wK, wV, bq, bk, bv, Qb, Kb, Vb, out);
    attn_kernel<<<1024, 256, 0, stream>>>(Qb, Kb, Vb, out + (size_t)NB * NH);
}